// Round 16
// baseline (198.324 us; speedup 1.0000x reference)
//
#include <hip/hip_runtime.h>
#include <math.h>

#define TT 2048   // tokens
#define Dm 1024   // model dim
#define DGc 256   // gate dim
#define Ec 8      // experts
#define Nc 9      // graph nodes
#define Hc 2048   // FFN hidden
#define PADMAX 5120
#define NT64MAX 80   // max 64-row expert tiles

typedef __attribute__((ext_vector_type(8))) short short8v;
typedef __attribute__((ext_vector_type(4))) float f32x4;

typedef __attribute__((address_space(1))) const void gvoid;
typedef __attribute__((address_space(3))) void svoid;

__device__ __forceinline__ void gll16(const void* g, void* l) {
    __builtin_amdgcn_global_load_lds((gvoid*)g, (svoid*)l, 16, 0, 0);
}

__device__ __forceinline__ float silu_f(float x) { return x / (1.f + __expf(-x)); }

__device__ __forceinline__ unsigned short bf16_rne(float f) {
    union { float f; unsigned u; } u; u.f = f;
    return (unsigned short)((u.u + 0x7fffu + ((u.u >> 16) & 1u)) >> 16);
}
__device__ __forceinline__ float bf16_to_f(unsigned short h) {
    union { unsigned u; float f; } u; u.u = ((unsigned)h) << 16; return u.f;
}
__device__ __forceinline__ void split2(float x, unsigned short& h, unsigned short& l) {
    h = bf16_rne(x);
    l = bf16_rne(x - bf16_to_f(h));
}

__device__ __forceinline__ void tsplit_body(const float* S, unsigned short* dh,
        unsigned short* dl, int R, int C, int r0, int c0, int tid, float (*t)[36]) {
    int i = tid >> 3, j4 = (tid & 7) * 4;
    *(float4*)&t[i][j4] = *(const float4*)&S[(size_t)(r0 + i) * C + c0 + j4];
    __syncthreads();
    int ci = tid >> 3, r4 = (tid & 7) * 4;
    ushort4 h, l;
    split2(t[r4 + 0][ci], h.x, l.x);
    split2(t[r4 + 1][ci], h.y, l.y);
    split2(t[r4 + 2][ci], h.z, l.z);
    split2(t[r4 + 3][ci], h.w, l.w);
    size_t o = (size_t)(c0 + ci) * R + r0 + r4;
    *(ushort4*)&dh[o] = h;
    *(ushort4*)&dl[o] = l;
}

// ---- 64x64 slab transpose+cast (hi only), rotated-LDS, 32B write segments ----
// rot(r) = 4*(r&15) + 8*(r>>4): float4 stores stay aligned; scalar reads 2-way.
__device__ __forceinline__ void tc64_body(const float* S, unsigned short* D,
        int R, int C, int r0, int c0, int tid, float* sb) {
    int r = tid >> 2;
    int cb = (tid & 3) * 16;
    const float* src = &S[(size_t)(r0 + r) * C + c0 + cb];
    int rot = 4 * (r & 15) + 8 * (r >> 4);
#pragma unroll
    for (int q = 0; q < 4; q++) {
        float4 v = *(const float4*)&src[q * 4];
        int cc = (cb + q * 4 + rot) & 63;
        *(float4*)&sb[r * 68 + cc] = v;
    }
    __syncthreads();
    int ci = tid >> 2;
    int rseg = (tid & 3) * 16;
    short8v o0, o1;
#pragma unroll
    for (int k = 0; k < 8; k++) {
        int r2 = rseg + k;
        int cc = (ci + 4 * (r2 & 15) + 8 * (r2 >> 4)) & 63;
        o0[k] = (short)bf16_rne(sb[r2 * 68 + cc]);
    }
#pragma unroll
    for (int k = 8; k < 16; k++) {
        int r2 = rseg + k;
        int cc = (ci + 4 * (r2 & 15) + 8 * (r2 >> 4)) & 63;
        o1[k - 8] = (short)bf16_rne(sb[r2 * 68 + cc]);
    }
    unsigned short* dst = &D[(size_t)(c0 + ci) * R + r0 + rseg];
    *(short8v*)&dst[0] = o0;
    *(short8v*)&dst[8] = o1;
}

// dispatch one tcast slab by flat index i (0..4095 = W1, 4096..8191 = W2)
__device__ __forceinline__ void tc_dispatch(int i, const float* W1, const float* W2,
        unsigned short* W1T, unsigned short* W2T, int tid, float* sb) {
    if (i < 4096) {
        int e = i >> 9, rem = i & 511;
        int r0 = (rem >> 5) * 64, c0 = (rem & 31) * 64;
        tc64_body(W1 + (size_t)e * Dm * Hc, W1T + (size_t)e * Dm * Hc,
                  Dm, Hc, r0, c0, tid, sb);
    } else {
        i -= 4096;
        int e = i >> 9, rem = i & 511;
        int r0 = (rem >> 4) * 64, c0 = (rem & 15) * 64;
        tc64_body(W2 + (size_t)e * Hc * Dm, W2T + (size_t)e * Hc * Dm,
                  Hc, Dm, r0, c0, tid, sb);
    }
}

// ---- standalone slab tcast (fallback path) ----
__global__ __launch_bounds__(256) void k_tcslab(const float* W1, const float* W2,
        unsigned short* W1T, unsigned short* W2T) {
    __shared__ float sb[64 * 68];
    tc_dispatch(blockIdx.x, W1, W2, W1T, W2T, threadIdx.x, sb);
}

// ---- fused prep: hs split | Wmlp tsplit | convW tsplit | expg partials |
//      loss tail + tcnt ----
__global__ __launch_bounds__(256) void k_prep(const float* hs, const float* Wmlp,
        const float* convW, const float* X, const float* Wst,
        const float* count, const float* lamb, const float* theta,
        unsigned short* hs_hi, unsigned short* hs_lo,
        unsigned short* WmT_h, unsigned short* WmT_l,
        unsigned short* WcT_h, unsigned short* WcT_l,
        float* Xpart, float* out, int* tcnt) {
    __shared__ float sbuf[32 * 36 > Ec * 64 ? 32 * 36 : Ec * 64];
    int b = blockIdx.x;
    int tid = threadIdx.x;
    if (b < 1024) {
        size_t i = ((size_t)b * 256 + tid) * 8;
        float4 v0 = *(const float4*)&hs[i];
        float4 v1 = *(const float4*)&hs[i + 4];
        ushort4 h0, l0, h1, l1;
        split2(v0.x, h0.x, l0.x); split2(v0.y, h0.y, l0.y);
        split2(v0.z, h0.z, l0.z); split2(v0.w, h0.w, l0.w);
        split2(v1.x, h1.x, l1.x); split2(v1.y, h1.y, l1.y);
        split2(v1.z, h1.z, l1.z); split2(v1.w, h1.w, l1.w);
        *(ushort4*)&hs_hi[i] = h0; *(ushort4*)&hs_hi[i + 4] = h1;
        *(ushort4*)&hs_lo[i] = l0; *(ushort4*)&hs_lo[i + 4] = l1;
    } else if (b < 1280) {
        int i2 = b - 1024;
        tsplit_body(Wmlp, WmT_h, WmT_l, Dm, DGc, (i2 >> 3) * 32, (i2 & 7) * 32,
                    tid, (float(*)[36])sbuf);
    } else if (b < 1472) {
        int i2 = b - 1280;
        int e = i2 >> 6, rem = i2 & 63;
        tsplit_body(convW + (size_t)e * DGc * DGc, WcT_h + (size_t)e * DGc * DGc,
                    WcT_l + (size_t)e * DGc * DGc, DGc, DGc,
                    (rem >> 3) * 32, (rem & 7) * 32, tid, (float(*)[36])sbuf);
    } else if (b < 1488) {
        float (*xs)[64] = (float(*)[64])sbuf;
        int p = b - 1472;
        int kb = p * 64;
        if (tid < 128) {
            int e = tid >> 4, k4 = (tid & 15) * 4;
            *(float4*)&xs[e][k4] = *(const float4*)&X[(size_t)e * Dm + kb + k4];
        }
        __syncthreads();
        float acc[Ec];
#pragma unroll
        for (int e = 0; e < Ec; e++) acc[e] = 0.f;
#pragma unroll 4
        for (int k = 0; k < 64; k++) {
            float w = Wst[(size_t)(kb + k) * DGc + tid];
#pragma unroll
            for (int e = 0; e < Ec; e++) acc[e] += xs[e][k] * w;
        }
#pragma unroll
        for (int e = 0; e < Ec; e++) Xpart[(size_t)p * Ec * DGc + e * DGc + tid] = acc[e];
    } else {
        if (tid < Ec) {
            float* loss = out + (size_t)TT * Dm;
            loss[(size_t)(TT + 1) * Ec + tid] = lamb[0];
            loss[(size_t)(TT + 2) * Ec + tid] = theta[0];
        }
        for (int i = tid; i < TT; i += 256) tcnt[i] = 0;
    }
}

// ---- Gpart[kb][m][g] = silu(expg)[m][kb*32..] . W0 chunk (no atomics) ----
__global__ __launch_bounds__(256) void k_gA(const float* Xpart, const float* W0,
                                            float* Gpart) {
    int g = threadIdx.x;
    int kb = blockIdx.x * 32;
    __shared__ float xs[Ec][32];
    {
        int m = g >> 5, k = g & 31;
        float s = 0.f;
#pragma unroll
        for (int p = 0; p < 16; p++)
            s += Xpart[(size_t)p * Ec * DGc + m * DGc + kb + k];
        xs[m][k] = silu_f(s);
    }
    __syncthreads();
    float acc[Ec];
#pragma unroll
    for (int e = 0; e < Ec; e++) acc[e] = 0.f;
#pragma unroll 4
    for (int k = 0; k < 32; k++) {
        float w = W0[(size_t)(kb + k) * DGc + g];
#pragma unroll
        for (int e = 0; e < Ec; e++) acc[e] += xs[e][k] * w;
    }
#pragma unroll
    for (int e = 0; e < Ec; e++)
        Gpart[(size_t)blockIdx.x * Ec * DGc + e * DGc + g] = acc[e];
}

// ---- S1[n] = sum_{m<8} A[n,m] * (sum_kb Gpart[kb][m]) ----
__global__ __launch_bounds__(256) void k_s1fin(const float* Gpart, const float* Ahat,
                                               float* S1) {
    int g = threadIdx.x;
    float Gl[Ec];
#pragma unroll
    for (int m = 0; m < Ec; m++) {
        float s = 0.f;
#pragma unroll
        for (int kb = 0; kb < 8; kb++)
            s += Gpart[(size_t)kb * Ec * DGc + m * DGc + g];
        Gl[m] = s;
    }
#pragma unroll
    for (int n = 0; n < Nc; n++) {
        float s = 0.f;
#pragma unroll
        for (int m = 0; m < Ec; m++) s += Ahat[n * Nc + m] * Gl[m];
        S1[n * DGc + g] = s;
    }
}

// ---- split-bf16 3-pass MFMA GEMM (gate path), 1D grid + tcast tail blocks ----
// EPI 0: write fp32 C.  EPI 1: silu+split bf16.  EPI 3: fp32 plane kz.
template<int BM, int KD, int KS, int BK, int EPI, int NX>
__global__ __launch_bounds__(256) void gemm4s(const unsigned short* Ah,
        const unsigned short* Al, const unsigned short* Bh, const unsigned short* Bl,
        float* Cf, unsigned short* Oh, unsigned short* Ol,
        const float* W1, const float* W2,
        unsigned short* W1T, unsigned short* W2T, int tcBase) {
    constexpr int FM = BM / 32;
    constexpr int KLEN = KD / KS;
    constexpr int CH = BK / 8;
    constexpr int RPP = 256 / CH;
    constexpr int APASS = BM / RPP;
    constexpr int BPASS = 128 / RPP;
    constexpr int KKS = BK / 32;
    constexpr int NGEMM = NX * 2 * KS;
    __shared__ __align__(16) unsigned char smem[(BM * BK + 128 * BK) * 4];
    int tid = threadIdx.x;
    int bid = blockIdx.x;
    if (bid >= NGEMM) {
        tc_dispatch(tcBase + (bid - NGEMM), W1, W2, W1T, W2T, tid, (float*)smem);
        return;
    }
    unsigned short* AsH = (unsigned short*)smem;
    unsigned short* AsL = AsH + BM * BK;
    unsigned short* BsH = AsL + BM * BK;
    unsigned short* BsL = BsH + 128 * BK;
    int m0 = (bid % NX) * BM;
    int rest = bid / NX;
    int n0 = (rest & 1) * 128;
    int kz = rest >> 1;
    int k0 = kz * KLEN;
    int lane = tid & 63, wid = tid >> 6;
    int wr = wid >> 1, wc = wid & 1, lo = lane & 15, hi = lane >> 4;

    f32x4 acc[FM][4];
#pragma unroll
    for (int m = 0; m < FM; m++)
#pragma unroll
        for (int n = 0; n < 4; n++) acc[m][n] = (f32x4)(0.f);

    int arow = tid / CH;
    int cswz = ((tid & (CH - 1)) ^ (arow & (CH - 1))) * 8;
    const unsigned short* AgH = Ah + (size_t)(m0 + arow) * KD + cswz;
    const unsigned short* AgL = Al + (size_t)(m0 + arow) * KD + cswz;
    const unsigned short* BgH = Bh + (size_t)(n0 + arow) * KD + cswz;
    const unsigned short* BgL = Bl + (size_t)(n0 + arow) * KD + cswz;

    for (int kb = k0; kb < k0 + KLEN; kb += BK) {
#pragma unroll
        for (int r = 0; r < APASS; r++) {
            gll16(AgH + (size_t)r * RPP * KD + kb, (char*)AsH + r * 4096 + tid * 16);
            gll16(AgL + (size_t)r * RPP * KD + kb, (char*)AsL + r * 4096 + tid * 16);
        }
#pragma unroll
        for (int r = 0; r < BPASS; r++) {
            gll16(BgH + (size_t)r * RPP * KD + kb, (char*)BsH + r * 4096 + tid * 16);
            gll16(BgL + (size_t)r * RPP * KD + kb, (char*)BsL + r * 4096 + tid * 16);
        }
        __syncthreads();
#pragma unroll
        for (int kk = 0; kk < KKS; kk++) {
            int csel = ((kk * 4 + hi) ^ (lo & (CH - 1))) * 8;
            short8v ah[FM], al[FM], bh[4], bl[4];
#pragma unroll
            for (int m = 0; m < FM; m++) {
                ah[m] = *(const short8v*)&AsH[(wr * (BM / 2) + m * 16 + lo) * BK + csel];
                al[m] = *(const short8v*)&AsL[(wr * (BM / 2) + m * 16 + lo) * BK + csel];
            }
#pragma unroll
            for (int n = 0; n < 4; n++) {
                bh[n] = *(const short8v*)&BsH[(wc * 64 + n * 16 + lo) * BK + csel];
                bl[n] = *(const short8v*)&BsL[(wc * 64 + n * 16 + lo) * BK + csel];
            }
#pragma unroll
            for (int m = 0; m < FM; m++)
#pragma unroll
                for (int n = 0; n < 4; n++)
                    acc[m][n] = __builtin_amdgcn_mfma_f32_16x16x32_bf16(ah[m], bh[n], acc[m][n], 0, 0, 0);
#pragma unroll
            for (int m = 0; m < FM; m++)
#pragma unroll
                for (int n = 0; n < 4; n++)
                    acc[m][n] = __builtin_amdgcn_mfma_f32_16x16x32_bf16(ah[m], bl[n], acc[m][n], 0, 0, 0);
#pragma unroll
            for (int m = 0; m < FM; m++)
#pragma unroll
                for (int n = 0; n < 4; n++)
                    acc[m][n] = __builtin_amdgcn_mfma_f32_16x16x32_bf16(al[m], bh[n], acc[m][n], 0, 0, 0);
        }
        __syncthreads();
    }

#pragma unroll
    for (int m = 0; m < FM; m++) {
#pragma unroll
        for (int n = 0; n < 4; n++) {
            int col = n0 + wc * 64 + n * 16 + lo;
#pragma unroll
            for (int r = 0; r < 4; r++) {
                int row = m0 + wr * (BM / 2) + m * 16 + hi * 4 + r;
                if (EPI == 0) {
                    Cf[(size_t)row * 256 + col] = acc[m][n][r];
                } else if (EPI == 3) {
                    Cf[((size_t)kz * TT + row) * 256 + col] = acc[m][n][r];
                } else {
                    float s = silu_f(acc[m][n][r]);
                    unsigned short h, l;
                    split2(s, h, l);
                    Oh[(size_t)row * 256 + col] = h;
                    Ol[(size_t)row * 256 + col] = l;
                }
            }
        }
    }
}

// ---- sum 4 xg planes + silu + split ----
__global__ __launch_bounds__(256) void k_finsplit(const float* src,
        unsigned short* dh, unsigned short* dl) {
    size_t i = ((size_t)blockIdx.x * 256 + threadIdx.x) * 4;
    float4 v0 = *(const float4*)&src[i];
    float4 v1 = *(const float4*)&src[(size_t)TT * DGc + i];
    float4 v2 = *(const float4*)&src[(size_t)2 * TT * DGc + i];
    float4 v3 = *(const float4*)&src[(size_t)3 * TT * DGc + i];
    float4 v = make_float4(v0.x + v1.x + v2.x + v3.x, v0.y + v1.y + v2.y + v3.y,
                           v0.z + v1.z + v2.z + v3.z, v0.w + v1.w + v2.w + v3.w);
    ushort4 h, l;
    split2(silu_f(v.x), h.x, l.x);
    split2(silu_f(v.y), h.y, l.y);
    split2(silu_f(v.z), h.z, l.z);
    split2(silu_f(v.w), h.w, l.w);
    *(ushort4*)&dh[i] = h;
    *(ushort4*)&dl[i] = l;
}

// ---- layer-1 build ----
__global__ __launch_bounds__(256) void k_l1(const float* ypart, const float* S1,
        const float* Ahat, unsigned short* nh, unsigned short* nl) {
    int t = blockIdx.x, g = threadIdx.x;
    float yv = ypart[(size_t)t * DGc + g] + ypart[(size_t)TT * DGc + (size_t)t * DGc + g];
#pragma unroll
    for (int n = 0; n < Nc; n++) {
        float c = Ahat[n * Nc + Ec];
        float s = silu_f(S1[n * DGc + g] + c * yv);
        unsigned short h, l;
        split2(s, h, l);
        size_t o = ((size_t)t * Nc + n) * DGc + g;
        nh[o] = h; nl[o] = l;
    }
}

// ---- mix: node[t,n] = silu(sum_m A[n,m] Z[t,m]) -> hi/lo ----
__global__ __launch_bounds__(256) void k_mix2(const float* Z, const float* Ahat,
        unsigned short* nh, unsigned short* nl) {
    int t = blockIdx.x, g = threadIdx.x;
    __shared__ float A[Nc * Nc];
    if (g < Nc * Nc) A[g] = Ahat[g];
    __syncthreads();
    float z[Nc];
#pragma unroll
    for (int m = 0; m < Nc; m++) z[m] = Z[((size_t)t * Nc + m) * DGc + g];
#pragma unroll
    for (int n = 0; n < Nc; n++) {
        float s = 0.f;
#pragma unroll
        for (int m = 0; m < Nc; m++) s += A[n * Nc + m] * z[m];
        s = silu_f(s);
        unsigned short h, l;
        split2(s, h, l);
        size_t o = ((size_t)t * Nc + n) * DGc + g;
        nh[o] = h; nl[o] = l;
    }
}

// ---- final mix + logits + softmax + top2; NO atomics ----
__global__ __launch_bounds__(256) void k_mix3(const float* Z, const float* Ahat,
        const float* wproj, float* out, int* sel, float* selv) {
    __shared__ float A[Nc * Nc];
    __shared__ float wp[DGc];
    int tid = threadIdx.x;
    if (tid < Nc * Nc) A[tid] = Ahat[tid];
    wp[tid] = wproj[tid];
    __syncthreads();
    int wid = tid >> 6, lane = tid & 63;
    int t = blockIdx.x * 4 + wid;
    float lg[Ec];
#pragma unroll
    for (int e = 0; e < Ec; e++) lg[e] = 0.f;
#pragma unroll
    for (int j = 0; j < 4; j++) {
        int g = j * 64 + lane;
        float z[Nc];
#pragma unroll
        for (int m = 0; m < Nc; m++) z[m] = Z[((size_t)t * Nc + m) * DGc + g];
#pragma unroll
        for (int e = 0; e < Ec; e++) {
            float s = 0.f;
#pragma unroll
            for (int m = 0; m < Nc; m++) s += A[e * Nc + m] * z[m];
            lg[e] += silu_f(s) * wp[g];
        }
    }
#pragma unroll
    for (int off = 32; off >= 1; off >>= 1) {
#pragma unroll
        for (int e = 0; e < Ec; e++) lg[e] += __shfl_xor(lg[e], off);
    }
    if (lane == 0) {
        float mx = -1e30f;
#pragma unroll
        for (int e = 0; e < Ec; e++) mx = fmaxf(mx, lg[e]);
        float pr[Ec], s = 0.f;
#pragma unroll
        for (int e = 0; e < Ec; e++) { pr[e] = __expf(lg[e] - mx); s += pr[e]; }
        float inv = 1.f / s;
        float* lrow = out + (size_t)TT * Dm + (size_t)t * Ec;
#pragma unroll
        for (int e = 0; e < Ec; e++) { pr[e] *= inv; lrow[e] = pr[e]; }
        int i0 = 0; float v0 = pr[0];
#pragma unroll
        for (int e = 1; e < Ec; e++) if (pr[e] > v0) { v0 = pr[e]; i0 = e; }
        int i1 = -1; float v1 = -1e30f;
#pragma unroll
        for (int e = 0; e < Ec; e++) if (e != i0 && pr[e] > v1) { v1 = pr[e]; i1 = e; }
        sel[t * 2] = i0; sel[t * 2 + 1] = i1;
        selv[t * 2] = v0; selv[t * 2 + 1] = v1;
    }
}

// ---- routing: one block per expert; wave-shfl scan, zero atomics ----
__global__ __launch_bounds__(256) void k_route(const int* sel, const float* selv,
        const float* count, float* out, int* cnt, int* toklist, float* wlist) {
    int e = blockIdx.x;
    int tid = threadIdx.x;
    int lane = tid & 63, wid = tid >> 6;
    __shared__ int wsum[4];
    __shared__ float wsumf[4];
    __shared__ int sbase;
    __shared__ float swtot;
    if (tid == 0) { sbase = 0; swtot = 0.f; }
    __syncthreads();
    for (int c = 0; c < TT; c += 256) {
        int t = c + tid;
        int i0 = sel[t * 2], i1 = sel[t * 2 + 1];
        float v0 = selv[t * 2], v1 = selv[t * 2 + 1];
        int f = 0; float vraw = 0.f;
        if (i0 == e) { f = 1; vraw = v0; }
        else if (i1 == e) { f = 1; vraw = v1; }
        float winv = 1.f / (v0 + v1);
        int ps = f;
        float pw = 2.f * vraw;
#pragma unroll
        for (int off = 1; off < 64; off <<= 1) {
            int s_ = __shfl_up(ps, off);
            float w_ = __shfl_up(pw, off);
            if (lane >= off) { ps += s_; pw += w_; }
        }
        if (lane == 63) { wsum[wid] = ps; wsumf[wid] = pw; }
        __syncthreads();
        int wpre = 0; float wpref = 0.f;
        for (int q = 0; q < wid; q++) { wpre += wsum[q]; wpref += wsumf[q]; }
        if (f) {
            int pos = sbase + wpre + ps - 1;
            toklist[e * TT + pos] = t;
            wlist[e * TT + pos] = vraw * winv;
        }
        __syncthreads();
        if (tid == 255) { sbase += wpre + ps; swtot += wpref + pw; }
        __syncthreads();
    }
    if (tid == 0) {
        cnt[e] = sbase;
        out[(size_t)TT * Dm + (size_t)TT * Ec + e] = count[e] + swtot;
    }
}

// ---- gather routed tokens (bf16 src); derives padded offsets from cnt ----
__global__ __launch_bounds__(256) void k_gather(const unsigned short* hs_hi,
        const int* cnt, const int* toklist, const float* wlist,
        unsigned short* xb, int* tcnt, int* tok2slot, float* tok2w) {
    int tid = threadIdx.x;
    int s = blockIdx.x * 2 + (tid >> 7);
    int j = (tid & 127) * 8;
    int e = -1, pos = 0, pad = 0, ce = 0;
#pragma unroll
    for (int q = 0; q < Ec; q++) {
        int cq = cnt[q];
        int span = ((cq + 63) >> 6) * 64;
        if (e < 0 && s < pad + span) { e = q; pos = s - pad; ce = cq; }
        pad += span;
    }
    int tok = -1; float w = 0.f;
    if (e >= 0 && pos < ce) { tok = toklist[e * TT + pos]; w = wlist[e * TT + pos]; }
    if (j == 0 && tok >= 0) {
        int idx = atomicAdd(&tcnt[tok], 1);
        tok2slot[tok * 2 + idx] = s;
        tok2w[tok * 2 + idx] = w;
    }
    short8v o;
    if (tok >= 0) {
        o = *(const short8v*)&hs_hi[(size_t)tok * Dm + j];
    } else {
        o = (short8v)(short)0;
    }
    *(short8v*)&xb[(size_t)s * Dm + j] = o;
}

// ---- FFN MFMA grouped GEMM: 64x128 tiles, BK=64, split-K planes, XCD remap ----
template<int KDIM, int NDIM, int MODE, int KS>
__global__ __launch_bounds__(256) void k_mfma(const unsigned short* Abuf,
        const unsigned short* Wt, const int* cnt, unsigned short* outp) {
    constexpr int NY = NDIM / 128;
    constexpr int KLEN = KDIM / KS;
    constexpr int CPX = (NT64MAX * NY * KS) / 8;
    int bid = blockIdx.x;
    int flat = (bid & 7) * CPX + (bid >> 3);
    int tx = flat / (NY * KS);
    int rem = flat % (NY * KS);
    int y = rem / KS, ks = rem % KS;
    int e = -1, m0 = 0, acc_t = 0, pad = 0;
#pragma unroll
    for (int q = 0; q < Ec; q++) {
        int te = (cnt[q] + 63) >> 6;
        if (e < 0 && tx < acc_t + te) { e = q; m0 = pad + (tx - acc_t) * 64; }
        acc_t += te; pad += te * 64;
    }
    if (e < 0) return;
    int n0 = y * 128;
    int k0 = ks * KLEN;
    __shared__ __align__(16) unsigned short As[64 * 64];    // 8 KB
    __shared__ __align__(16) unsigned short Bs[128 * 64];   // 16 KB
    int tid = threadIdx.x;
    int lane = tid & 63;
    int wid = tid >> 6;
    int wr = wid >> 1, wc = wid & 1;
    int lo = lane & 15, hi = lane >> 4;

    f32x4 acc[2][4];
#pragma unroll
    for (int m = 0; m < 2; m++)
#pragma unroll
        for (int n = 0; n < 4; n++) acc[m][n] = (f32x4)(0.f);

    int arow = tid >> 3;
    int cswz = ((tid & 7) ^ (arow & 7)) * 8;
    const unsigned short* Ag = Abuf + (size_t)(m0 + arow) * KDIM + k0 + cswz;
    const unsigned short* Bg = Wt + (size_t)e * NDIM * KDIM
                               + (size_t)(n0 + arow) * KDIM + k0 + cswz;

    for (int kb = 0; kb < KLEN; kb += 64) {
        gll16(Ag + kb,                          (char*)As + tid * 16);
        gll16(Ag + 32 * (size_t)KDIM + kb,      (char*)As + 4096 + tid * 16);
        gll16(Bg + kb,                          (char*)Bs + tid * 16);
        gll16(Bg + 32 * (size_t)KDIM + kb,      (char*)Bs + 4096 + tid * 16);
        gll16(Bg + 64 * (size_t)KDIM + kb,      (char*)Bs + 8192 + tid * 16);
        gll16(Bg + 96 * (size_t)KDIM + kb,      (char*)Bs + 12288 + tid * 16);
        __syncthreads();
#pragma unroll
        for (int kk = 0; kk < 2; kk++) {
            int csel = ((kk * 4 + hi) ^ (lo & 7)) * 8;
            short8v a[2], b[4];
#pragma unroll
            for (int m = 0; m < 2; m++)
                a[m] = *(const short8v*)&As[(wr * 32 + m * 16 + lo) * 64 + csel];
#pragma unroll
            for (int n = 0; n < 4; n++)
                b[n] = *(const short8v*)&Bs[(wc * 64 + n * 16 + lo) * 64 + csel];
#pragma unroll
            for (int m = 0; m < 2; m++)
#pragma unroll
                for (int n = 0; n < 4; n++)
                    acc[m][n] = __builtin_amdgcn_mfma_f32_16x16x32_bf16(a[m], b[n], acc[m][n], 0, 0, 0);
        }
        __syncthreads();
    }

#pragma unroll
    for (int m = 0; m < 2; m++) {
#pragma unroll
        for (int n = 0; n < 4; n++) {
            int col = n0 + wc * 64 + n * 16 + lo;
#pragma unroll
            for (int r = 0; r < 4; r++) {
                int row = m0 + wr * 32 + m * 16 + hi * 4 + r;
                if (MODE == 0) {
                    outp[(size_t)row * NDIM + col] = bf16_rne(silu_f(acc[m][n][r]));
                } else {
                    outp[((size_t)ks * PADMAX + row) * Dm + col] = bf16_rne(acc[m][n][r]);
                }
            }
        }
    }
}

// ---- combine: out[t] = w0*(P0[s0]+P1[s0]) + w1*(P0[s1]+P1[s1]) ----
__global__ __launch_bounds__(256) void k_combine(const unsigned short* Opart,
        const int* tok2slot, const float* tok2w, float* out) {
    int t = blockIdx.x, tid = threadIdx.x;
    int s0 = tok2slot[t * 2], s1 = tok2slot[t * 2 + 1];
    float w0 = tok2w[t * 2], w1 = tok2w[t * 2 + 1];
    int c = tid * 4;
    ushort4 a0 = *(const ushort4*)&Opart[(size_t)s0 * Dm + c];
    ushort4 a1 = *(const ushort4*)&Opart[((size_t)PADMAX + s0) * Dm + c];
    ushort4 b0 = *(const ushort4*)&Opart[(size_t)s1 * Dm + c];
    ushort4 b1 = *(const ushort4*)&Opart[((size_t)PADMAX + s1) * Dm + c];
    float4 r;
    r.x = w0 * (bf16_to_f(a0.x) + bf16_to_f(a1.x)) + w1 * (bf16_to_f(b0.x) + bf16_to_f(b1.x));
    r.y = w0 * (bf16_to_f(a0.y) + bf16_to_f(a1.y)) + w1 * (bf16_to_f(b0.y) + bf16_to_f(b1.y));
    r.z = w0 * (bf16_to_f(a0.z) + bf16_to_f(a1.z)) + w1 * (bf16_to_f(b0.z) + bf16_to_f(b1.z));
    r.w = w0 * (bf16_to_f(a0.w) + bf16_to_f(a1.w)) + w1 * (bf16_to_f(b0.w) + bf16_to_f(b1.w));
    *(float4*)&out[(size_t)t * Dm + c] = r;
}

extern "C" void kernel_launch(void* const* d_in, const int* in_sizes, int n_in,
                              void* d_out, int out_size, void* d_ws, size_t ws_size,
                              hipStream_t stream) {
    const float* hs    = (const float*)d_in[0];
    const float* X     = (const float*)d_in[1];
    const float* Wmlp  = (const float*)d_in[2];
    const float* Wst   = (const float*)d_in[3];
    const float* convW = (const float*)d_in[4];
    const float* wproj = (const float*)d_in[5];
    const float* W1    = (const float*)d_in[6];
    const float* W2    = (const float*)d_in[7];
    const float* lamb  = (const float*)d_in[8];
    const float* theta = (const float*)d_in[9];
    const float* count = (const float*)d_in[10];
    const float* Ahat  = (const float*)d_in[11];
    float* out = (float*)d_out;
    char* ws = (char*)d_ws;

    // persistent layout
    int*            cnt     = (int*)(ws + 8192);
    float*          S1      = (float*)(ws + 9728);
    int*            toklist = (int*)(ws + 20480);
    float*          wlist   = (float*)(ws + 86016);
    int*            tcnt    = (int*)(ws + 151552);
    int*            tok2slot= (int*)(ws + 159744);
    float*          tok2w   = (float*)(ws + 176128);
    int*            sel     = (int*)(ws + 192512);
    float*          selv    = (float*)(ws + 208896);
    unsigned short* xb      = (unsigned short*)(ws + 237568);   // 10.5 MB
    unsigned short* W1T     = (unsigned short*)(ws + 10723328); // 33.5 MB
    unsigned short* W2T     = (unsigned short*)(ws + 44277760); // 33.5 MB
    unsigned short* hb      = (unsigned short*)(ws + 77832192); // 21 MB, ends 98.8 MB
    unsigned short* Opart   = W1T;                              // dead after up-GEMM

    bool big = ws_size >= (size_t)174063616;   // 166 MiB
    char* G = big ? (ws + 98803712) : (ws + 10723328);
    unsigned short* hs_hi = (unsigned short*)(G);
    unsigned short* hs_lo = (unsigned short*)(G + 4194304);
    unsigned short* WmT_h = (unsigned short*)(G + 8388608);
    unsigned short* WmT_l = (unsigned short*)(G + 8912896);
    unsigned short* WcT_h = (unsigned short*)(G + 9437184);
    unsigned short* WcT_l = (unsigned short*)(G + 9830400);
    unsigned short* xg_h  = (unsigned short*)(G + 10223616);
    unsigned short* xg_l  = (unsigned short*)(G + 11272192);
    float*          ypart = (float*)(G + 12320768);
    unsigned short* n_h   = (unsigned short*)(G + 16515072);
    unsigned short* n_l   = (unsigned short*)(G + 25952256);
    float*          Zb    = (float*)(G + 35389440);
    float*          Gpart = (float*)(G + 54263808);
    float*          xgp   = (float*)(G + 54329344);
    float*          Xpart = (float*)(G + 62717952);

    // tcast tail-block distribution (big path only; 8192 slabs total)
    int tc_xg = big ? 2048 : 0;
    int tc_l2 = big ? 3072 : 0;
    int tc_l3 = big ? 3072 : 0;

    k_prep<<<1489, 256, 0, stream>>>(hs, Wmlp, convW, X, Wst, count, lamb,
                                     theta, hs_hi, hs_lo, WmT_h, WmT_l,
                                     WcT_h, WcT_l, Xpart, out, tcnt);
    k_gA<<<DGc / 32, 256, 0, stream>>>(Xpart, convW, Gpart);
    k_s1fin<<<1, 256, 0, stream>>>(Gpart, Ahat, S1);
    // xg = silu(hs @ Wmlp): KS=4 plane store (+ tcast tail)
    gemm4s<64, Dm, 4, 64, 3, 32><<<256 + tc_xg, 256, 0, stream>>>(
        hs_hi, hs_lo, WmT_h, WmT_l, xgp, nullptr, nullptr,
        W1, W2, W1T, W2T, 0);
    k_finsplit<<<TT * DGc / 1024, 256, 0, stream>>>(xgp, xg_h, xg_l);
    // y = xg @ convW[0]: KS=2 plane store (no tail)
    gemm4s<64, DGc, 2, 64, 3, 32><<<128, 256, 0, stream>>>(
        xg_h, xg_l, WcT_h, WcT_l, ypart, nullptr, nullptr,
        W1, W2, W1T, W2T, 0);
    k_l1<<<TT, 256, 0, stream>>>(ypart, S1, Ahat, n_h, n_l);
    // layer 2 (+ tcast tail)
    gemm4s<64, DGc, 1, 64, 0, 288><<<576 + tc_l2, 256, 0, stream>>>(
        n_h, n_l, WcT_h + 65536, WcT_l + 65536, Zb, nullptr, nullptr,
        W1, W2, W1T, W2T, 2048);
    k_mix2<<<TT, 256, 0, stream>>>(Zb, Ahat, n_h, n_l);
    // layer 3 (+ tcast tail)
    gemm4s<64, DGc, 1, 64, 0, 288><<<576 + tc_l3, 256, 0, stream>>>(
        n_h, n_l, WcT_h + 131072, WcT_l + 131072, Zb, nullptr, nullptr,
        W1, W2, W1T, W2T, 5120);
    k_mix3<<<TT / 4, 256, 0, stream>>>(Zb, Ahat, wproj, out, sel, selv);
    k_route<<<Ec, 256, 0, stream>>>(sel, selv, count, out, cnt, toklist, wlist);
    k_gather<<<PADMAX / 2, 256, 0, stream>>>(hs_hi, cnt, toklist, wlist,
                                             xb, tcnt, tok2slot, tok2w);
    if (!big) {
        // fallback: hs_hi aliased W1T, so tcast must follow gather
        k_tcslab<<<8192, 256, 0, stream>>>(W1, W2, W1T, W2T);
    }
    k_mfma<Dm, Hc, 0, 1><<<NT64MAX * (Hc / 128), 256, 0, stream>>>(
        xb, W1T, cnt, hb);
    k_mfma<Hc, Dm, 1, 2><<<NT64MAX * (Dm / 128) * 2, 256, 0, stream>>>(
        hb, W2T, cnt, Opart);
    k_combine<<<TT, 256, 0, stream>>>(Opart, tok2slot, tok2w, out);
}

// Round 17
// 191.803 us; speedup vs baseline: 1.0340x; 1.0340x over previous
//
#include <hip/hip_runtime.h>
#include <math.h>

#define TT 2048   // tokens
#define Dm 1024   // model dim
#define DGc 256   // gate dim
#define Ec 8      // experts
#define Nc 9      // graph nodes
#define Hc 2048   // FFN hidden
#define PADMAX 5120
#define NT64MAX 80   // max 64-row expert tiles

typedef __attribute__((ext_vector_type(8))) short short8v;
typedef __attribute__((ext_vector_type(4))) float f32x4;

typedef __attribute__((address_space(1))) const void gvoid;
typedef __attribute__((address_space(3))) void svoid;

__device__ __forceinline__ void gll16(const void* g, void* l) {
    __builtin_amdgcn_global_load_lds((gvoid*)g, (svoid*)l, 16, 0, 0);
}

__device__ __forceinline__ float silu_f(float x) { return x / (1.f + __expf(-x)); }

__device__ __forceinline__ unsigned short bf16_rne(float f) {
    union { float f; unsigned u; } u; u.f = f;
    return (unsigned short)((u.u + 0x7fffu + ((u.u >> 16) & 1u)) >> 16);
}
__device__ __forceinline__ float bf16_to_f(unsigned short h) {
    union { unsigned u; float f; } u; u.u = ((unsigned)h) << 16; return u.f;
}
__device__ __forceinline__ void split2(float x, unsigned short& h, unsigned short& l) {
    h = bf16_rne(x);
    l = bf16_rne(x - bf16_to_f(h));
}

__device__ __forceinline__ void tsplit_body(const float* S, unsigned short* dh,
        unsigned short* dl, int R, int C, int r0, int c0, int tid, float (*t)[36]) {
    int i = tid >> 3, j4 = (tid & 7) * 4;
    *(float4*)&t[i][j4] = *(const float4*)&S[(size_t)(r0 + i) * C + c0 + j4];
    __syncthreads();
    int ci = tid >> 3, r4 = (tid & 7) * 4;
    ushort4 h, l;
    split2(t[r4 + 0][ci], h.x, l.x);
    split2(t[r4 + 1][ci], h.y, l.y);
    split2(t[r4 + 2][ci], h.z, l.z);
    split2(t[r4 + 3][ci], h.w, l.w);
    size_t o = (size_t)(c0 + ci) * R + r0 + r4;
    *(ushort4*)&dh[o] = h;
    *(ushort4*)&dl[o] = l;
}

// ---- 64x64 slab transpose+cast (hi only), rotated-LDS, 32B write segments ----
// rot(r) = 4*(r&15) + 8*(r>>4): float4 stores stay 16B-aligned; scalar reads
// at most 2-way (rows 16 apart no longer collide).
__device__ __forceinline__ void tc64_body(const float* S, unsigned short* D,
        int R, int C, int r0, int c0, int tid, float* sb) {
    int r = tid >> 2;
    int cb = (tid & 3) * 16;
    const float* src = &S[(size_t)(r0 + r) * C + c0 + cb];
    int rot = 4 * (r & 15) + 8 * (r >> 4);
#pragma unroll
    for (int q = 0; q < 4; q++) {
        float4 v = *(const float4*)&src[q * 4];
        int cc = (cb + q * 4 + rot) & 63;
        *(float4*)&sb[r * 68 + cc] = v;
    }
    __syncthreads();
    int ci = tid >> 2;
    int rseg = (tid & 3) * 16;
    short8v o0, o1;
#pragma unroll
    for (int k = 0; k < 8; k++) {
        int r2 = rseg + k;
        int cc = (ci + 4 * (r2 & 15) + 8 * (r2 >> 4)) & 63;
        o0[k] = (short)bf16_rne(sb[r2 * 68 + cc]);
    }
#pragma unroll
    for (int k = 8; k < 16; k++) {
        int r2 = rseg + k;
        int cc = (ci + 4 * (r2 & 15) + 8 * (r2 >> 4)) & 63;
        o1[k - 8] = (short)bf16_rne(sb[r2 * 68 + cc]);
    }
    unsigned short* dst = &D[(size_t)(c0 + ci) * R + r0 + rseg];
    *(short8v*)&dst[0] = o0;
    *(short8v*)&dst[8] = o1;
}

// ---- standalone slab tcast (fallback path) ----
__global__ __launch_bounds__(256) void k_tcslab(const float* W1, const float* W2,
        unsigned short* W1T, unsigned short* W2T) {
    __shared__ float sb[64 * 68];
    int i = blockIdx.x;
    if (i < 4096) {
        int e = i >> 9, rem = i & 511;
        int r0 = (rem >> 5) * 64, c0 = (rem & 31) * 64;
        tc64_body(W1 + (size_t)e * Dm * Hc, W1T + (size_t)e * Dm * Hc,
                  Dm, Hc, r0, c0, threadIdx.x, sb);
    } else {
        i -= 4096;
        int e = i >> 9, rem = i & 511;
        int r0 = (rem >> 4) * 64, c0 = (rem & 15) * 64;
        tc64_body(W2 + (size_t)e * Hc * Dm, W2T + (size_t)e * Hc * Dm,
                  Hc, Dm, r0, c0, threadIdx.x, sb);
    }
}

// ---- fused prep: hs split | Wmlp tsplit | convW tsplit | expg partials |
//      loss tail + tcnt | (big path) W1/W2 slab tcasts ----
__global__ __launch_bounds__(256) void k_prep(const float* hs, const float* Wmlp,
        const float* convW, const float* X, const float* Wst,
        const float* count, const float* lamb, const float* theta,
        unsigned short* hs_hi, unsigned short* hs_lo,
        unsigned short* WmT_h, unsigned short* WmT_l,
        unsigned short* WcT_h, unsigned short* WcT_l,
        float* Xpart, float* out, int* tcnt,
        const float* W1, const float* W2,
        unsigned short* W1T, unsigned short* W2T) {
    __shared__ float sbuf[64 * 68];
    int b = blockIdx.x;
    int tid = threadIdx.x;
    if (b < 1024) {
        size_t i = ((size_t)b * 256 + tid) * 8;
        float4 v0 = *(const float4*)&hs[i];
        float4 v1 = *(const float4*)&hs[i + 4];
        ushort4 h0, l0, h1, l1;
        split2(v0.x, h0.x, l0.x); split2(v0.y, h0.y, l0.y);
        split2(v0.z, h0.z, l0.z); split2(v0.w, h0.w, l0.w);
        split2(v1.x, h1.x, l1.x); split2(v1.y, h1.y, l1.y);
        split2(v1.z, h1.z, l1.z); split2(v1.w, h1.w, l1.w);
        *(ushort4*)&hs_hi[i] = h0; *(ushort4*)&hs_hi[i + 4] = h1;
        *(ushort4*)&hs_lo[i] = l0; *(ushort4*)&hs_lo[i + 4] = l1;
    } else if (b < 1280) {
        int i2 = b - 1024;
        tsplit_body(Wmlp, WmT_h, WmT_l, Dm, DGc, (i2 >> 3) * 32, (i2 & 7) * 32,
                    tid, (float(*)[36])sbuf);
    } else if (b < 1472) {
        int i2 = b - 1280;
        int e = i2 >> 6, rem = i2 & 63;
        tsplit_body(convW + (size_t)e * DGc * DGc, WcT_h + (size_t)e * DGc * DGc,
                    WcT_l + (size_t)e * DGc * DGc, DGc, DGc,
                    (rem >> 3) * 32, (rem & 7) * 32, tid, (float(*)[36])sbuf);
    } else if (b < 1488) {
        float (*xs)[64] = (float(*)[64])sbuf;
        int p = b - 1472;
        int kb = p * 64;
        if (tid < 128) {
            int e = tid >> 4, k4 = (tid & 15) * 4;
            *(float4*)&xs[e][k4] = *(const float4*)&X[(size_t)e * Dm + kb + k4];
        }
        __syncthreads();
        float acc[Ec];
#pragma unroll
        for (int e = 0; e < Ec; e++) acc[e] = 0.f;
#pragma unroll 4
        for (int k = 0; k < 64; k++) {
            float w = Wst[(size_t)(kb + k) * DGc + tid];
#pragma unroll
            for (int e = 0; e < Ec; e++) acc[e] += xs[e][k] * w;
        }
#pragma unroll
        for (int e = 0; e < Ec; e++) Xpart[(size_t)p * Ec * DGc + e * DGc + tid] = acc[e];
    } else if (b == 1488) {
        if (tid < Ec) {
            float* loss = out + (size_t)TT * Dm;
            loss[(size_t)(TT + 1) * Ec + tid] = lamb[0];
            loss[(size_t)(TT + 2) * Ec + tid] = theta[0];
        }
        for (int i = tid; i < TT; i += 256) tcnt[i] = 0;
    } else {
        int i = b - 1489;
        if (i < 4096) {
            int e = i >> 9, rem = i & 511;
            int r0 = (rem >> 5) * 64, c0 = (rem & 31) * 64;
            tc64_body(W1 + (size_t)e * Dm * Hc, W1T + (size_t)e * Dm * Hc,
                      Dm, Hc, r0, c0, tid, sbuf);
        } else {
            i -= 4096;
            int e = i >> 9, rem = i & 511;
            int r0 = (rem >> 4) * 64, c0 = (rem & 15) * 64;
            tc64_body(W2 + (size_t)e * Hc * Dm, W2T + (size_t)e * Hc * Dm,
                      Hc, Dm, r0, c0, tid, sbuf);
        }
    }
}

// ---- Gpart[kb][m][g] = silu(expg)[m][kb*32..] . W0 chunk (no atomics) ----
__global__ __launch_bounds__(256) void k_gA(const float* Xpart, const float* W0,
                                            float* Gpart) {
    int g = threadIdx.x;
    int kb = blockIdx.x * 32;
    __shared__ float xs[Ec][32];
    {
        int m = g >> 5, k = g & 31;
        float s = 0.f;
#pragma unroll
        for (int p = 0; p < 16; p++)
            s += Xpart[(size_t)p * Ec * DGc + m * DGc + kb + k];
        xs[m][k] = silu_f(s);
    }
    __syncthreads();
    float acc[Ec];
#pragma unroll
    for (int e = 0; e < Ec; e++) acc[e] = 0.f;
#pragma unroll 4
    for (int k = 0; k < 32; k++) {
        float w = W0[(size_t)(kb + k) * DGc + g];
#pragma unroll
        for (int e = 0; e < Ec; e++) acc[e] += xs[e][k] * w;
    }
#pragma unroll
    for (int e = 0; e < Ec; e++)
        Gpart[(size_t)blockIdx.x * Ec * DGc + e * DGc + g] = acc[e];
}

// ---- S1[n] = sum_{m<8} A[n,m] * (sum_kb Gpart[kb][m]) ----
__global__ __launch_bounds__(256) void k_s1fin(const float* Gpart, const float* Ahat,
                                               float* S1) {
    int g = threadIdx.x;
    float Gl[Ec];
#pragma unroll
    for (int m = 0; m < Ec; m++) {
        float s = 0.f;
#pragma unroll
        for (int kb = 0; kb < 8; kb++)
            s += Gpart[(size_t)kb * Ec * DGc + m * DGc + g];
        Gl[m] = s;
    }
#pragma unroll
    for (int n = 0; n < Nc; n++) {
        float s = 0.f;
#pragma unroll
        for (int m = 0; m < Ec; m++) s += Ahat[n * Nc + m] * Gl[m];
        S1[n * DGc + g] = s;
    }
}

// ---- split-bf16 3-pass MFMA GEMM (gate path), templated BK ----
template<int BM, int KD, int KS, int BK, int EPI>
__global__ __launch_bounds__(256) void gemm4s(const unsigned short* Ah,
        const unsigned short* Al, const unsigned short* Bh, const unsigned short* Bl,
        float* Cf, unsigned short* Oh, unsigned short* Ol) {
    constexpr int FM = BM / 32;
    constexpr int KLEN = KD / KS;
    constexpr int CH = BK / 8;
    constexpr int RPP = 256 / CH;
    constexpr int APASS = BM / RPP;
    constexpr int BPASS = 128 / RPP;
    constexpr int KKS = BK / 32;
    int m0 = blockIdx.x * BM, n0 = blockIdx.y * 128;
    int k0 = blockIdx.z * KLEN;
    __shared__ __align__(16) unsigned short AsH[BM * BK];
    __shared__ __align__(16) unsigned short AsL[BM * BK];
    __shared__ __align__(16) unsigned short BsH[128 * BK];
    __shared__ __align__(16) unsigned short BsL[128 * BK];
    int tid = threadIdx.x, lane = tid & 63, wid = tid >> 6;
    int wr = wid >> 1, wc = wid & 1, lo = lane & 15, hi = lane >> 4;

    f32x4 acc[FM][4];
#pragma unroll
    for (int m = 0; m < FM; m++)
#pragma unroll
        for (int n = 0; n < 4; n++) acc[m][n] = (f32x4)(0.f);

    int arow = tid / CH;
    int cswz = ((tid & (CH - 1)) ^ (arow & (CH - 1))) * 8;
    const unsigned short* AgH = Ah + (size_t)(m0 + arow) * KD + cswz;
    const unsigned short* AgL = Al + (size_t)(m0 + arow) * KD + cswz;
    const unsigned short* BgH = Bh + (size_t)(n0 + arow) * KD + cswz;
    const unsigned short* BgL = Bl + (size_t)(n0 + arow) * KD + cswz;

    for (int kb = k0; kb < k0 + KLEN; kb += BK) {
#pragma unroll
        for (int r = 0; r < APASS; r++) {
            gll16(AgH + (size_t)r * RPP * KD + kb, (char*)AsH + r * 4096 + tid * 16);
            gll16(AgL + (size_t)r * RPP * KD + kb, (char*)AsL + r * 4096 + tid * 16);
        }
#pragma unroll
        for (int r = 0; r < BPASS; r++) {
            gll16(BgH + (size_t)r * RPP * KD + kb, (char*)BsH + r * 4096 + tid * 16);
            gll16(BgL + (size_t)r * RPP * KD + kb, (char*)BsL + r * 4096 + tid * 16);
        }
        __syncthreads();
#pragma unroll
        for (int kk = 0; kk < KKS; kk++) {
            int csel = ((kk * 4 + hi) ^ (lo & (CH - 1))) * 8;
            short8v ah[FM], al[FM], bh[4], bl[4];
#pragma unroll
            for (int m = 0; m < FM; m++) {
                ah[m] = *(const short8v*)&AsH[(wr * (BM / 2) + m * 16 + lo) * BK + csel];
                al[m] = *(const short8v*)&AsL[(wr * (BM / 2) + m * 16 + lo) * BK + csel];
            }
#pragma unroll
            for (int n = 0; n < 4; n++) {
                bh[n] = *(const short8v*)&BsH[(wc * 64 + n * 16 + lo) * BK + csel];
                bl[n] = *(const short8v*)&BsL[(wc * 64 + n * 16 + lo) * BK + csel];
            }
#pragma unroll
            for (int m = 0; m < FM; m++)
#pragma unroll
                for (int n = 0; n < 4; n++)
                    acc[m][n] = __builtin_amdgcn_mfma_f32_16x16x32_bf16(ah[m], bh[n], acc[m][n], 0, 0, 0);
#pragma unroll
            for (int m = 0; m < FM; m++)
#pragma unroll
                for (int n = 0; n < 4; n++)
                    acc[m][n] = __builtin_amdgcn_mfma_f32_16x16x32_bf16(ah[m], bl[n], acc[m][n], 0, 0, 0);
#pragma unroll
            for (int m = 0; m < FM; m++)
#pragma unroll
                for (int n = 0; n < 4; n++)
                    acc[m][n] = __builtin_amdgcn_mfma_f32_16x16x32_bf16(al[m], bh[n], acc[m][n], 0, 0, 0);
        }
        __syncthreads();
    }

#pragma unroll
    for (int m = 0; m < FM; m++) {
#pragma unroll
        for (int n = 0; n < 4; n++) {
            int col = n0 + wc * 64 + n * 16 + lo;
#pragma unroll
            for (int r = 0; r < 4; r++) {
                int row = m0 + wr * (BM / 2) + m * 16 + hi * 4 + r;
                if (EPI == 0) {
                    Cf[(size_t)row * 256 + col] = acc[m][n][r];
                } else if (EPI == 3) {
                    Cf[((size_t)blockIdx.z * TT + row) * 256 + col] = acc[m][n][r];
                } else {
                    float s = silu_f(acc[m][n][r]);
                    unsigned short h, l;
                    split2(s, h, l);
                    Oh[(size_t)row * 256 + col] = h;
                    Ol[(size_t)row * 256 + col] = l;
                }
            }
        }
    }
}

// ---- sum 4 xg planes + silu + split ----
__global__ __launch_bounds__(256) void k_finsplit(const float* src,
        unsigned short* dh, unsigned short* dl) {
    size_t i = ((size_t)blockIdx.x * 256 + threadIdx.x) * 4;
    float4 v0 = *(const float4*)&src[i];
    float4 v1 = *(const float4*)&src[(size_t)TT * DGc + i];
    float4 v2 = *(const float4*)&src[(size_t)2 * TT * DGc + i];
    float4 v3 = *(const float4*)&src[(size_t)3 * TT * DGc + i];
    float4 v = make_float4(v0.x + v1.x + v2.x + v3.x, v0.y + v1.y + v2.y + v3.y,
                           v0.z + v1.z + v2.z + v3.z, v0.w + v1.w + v2.w + v3.w);
    ushort4 h, l;
    split2(silu_f(v.x), h.x, l.x);
    split2(silu_f(v.y), h.y, l.y);
    split2(silu_f(v.z), h.z, l.z);
    split2(silu_f(v.w), h.w, l.w);
    *(ushort4*)&dh[i] = h;
    *(ushort4*)&dl[i] = l;
}

// ---- layer-1 build ----
__global__ __launch_bounds__(256) void k_l1(const float* ypart, const float* S1,
        const float* Ahat, unsigned short* nh, unsigned short* nl) {
    int t = blockIdx.x, g = threadIdx.x;
    float yv = ypart[(size_t)t * DGc + g] + ypart[(size_t)TT * DGc + (size_t)t * DGc + g];
#pragma unroll
    for (int n = 0; n < Nc; n++) {
        float c = Ahat[n * Nc + Ec];
        float s = silu_f(S1[n * DGc + g] + c * yv);
        unsigned short h, l;
        split2(s, h, l);
        size_t o = ((size_t)t * Nc + n) * DGc + g;
        nh[o] = h; nl[o] = l;
    }
}

// ---- mix: node[t,n] = silu(sum_m A[n,m] Z[t,m]) -> hi/lo ----
__global__ __launch_bounds__(256) void k_mix2(const float* Z, const float* Ahat,
        unsigned short* nh, unsigned short* nl) {
    int t = blockIdx.x, g = threadIdx.x;
    __shared__ float A[Nc * Nc];
    if (g < Nc * Nc) A[g] = Ahat[g];
    __syncthreads();
    float z[Nc];
#pragma unroll
    for (int m = 0; m < Nc; m++) z[m] = Z[((size_t)t * Nc + m) * DGc + g];
#pragma unroll
    for (int n = 0; n < Nc; n++) {
        float s = 0.f;
#pragma unroll
        for (int m = 0; m < Nc; m++) s += A[n * Nc + m] * z[m];
        s = silu_f(s);
        unsigned short h, l;
        split2(s, h, l);
        size_t o = ((size_t)t * Nc + n) * DGc + g;
        nh[o] = h; nl[o] = l;
    }
}

// ---- final mix + logits + softmax + top2; NO atomics ----
__global__ __launch_bounds__(256) void k_mix3(const float* Z, const float* Ahat,
        const float* wproj, float* out, int* sel, float* selv) {
    __shared__ float A[Nc * Nc];
    __shared__ float wp[DGc];
    int tid = threadIdx.x;
    if (tid < Nc * Nc) A[tid] = Ahat[tid];
    wp[tid] = wproj[tid];
    __syncthreads();
    int wid = tid >> 6, lane = tid & 63;
    int t = blockIdx.x * 4 + wid;
    float lg[Ec];
#pragma unroll
    for (int e = 0; e < Ec; e++) lg[e] = 0.f;
#pragma unroll
    for (int j = 0; j < 4; j++) {
        int g = j * 64 + lane;
        float z[Nc];
#pragma unroll
        for (int m = 0; m < Nc; m++) z[m] = Z[((size_t)t * Nc + m) * DGc + g];
#pragma unroll
        for (int e = 0; e < Ec; e++) {
            float s = 0.f;
#pragma unroll
            for (int m = 0; m < Nc; m++) s += A[e * Nc + m] * z[m];
            lg[e] += silu_f(s) * wp[g];
        }
    }
#pragma unroll
    for (int off = 32; off >= 1; off >>= 1) {
#pragma unroll
        for (int e = 0; e < Ec; e++) lg[e] += __shfl_xor(lg[e], off);
    }
    if (lane == 0) {
        float mx = -1e30f;
#pragma unroll
        for (int e = 0; e < Ec; e++) mx = fmaxf(mx, lg[e]);
        float pr[Ec], s = 0.f;
#pragma unroll
        for (int e = 0; e < Ec; e++) { pr[e] = __expf(lg[e] - mx); s += pr[e]; }
        float inv = 1.f / s;
        float* lrow = out + (size_t)TT * Dm + (size_t)t * Ec;
#pragma unroll
        for (int e = 0; e < Ec; e++) { pr[e] *= inv; lrow[e] = pr[e]; }
        int i0 = 0; float v0 = pr[0];
#pragma unroll
        for (int e = 1; e < Ec; e++) if (pr[e] > v0) { v0 = pr[e]; i0 = e; }
        int i1 = -1; float v1 = -1e30f;
#pragma unroll
        for (int e = 0; e < Ec; e++) if (e != i0 && pr[e] > v1) { v1 = pr[e]; i1 = e; }
        sel[t * 2] = i0; sel[t * 2 + 1] = i1;
        selv[t * 2] = v0; selv[t * 2 + 1] = v1;
    }
}

// ---- routing: one block per expert; wave-shfl scan, zero atomics ----
__global__ __launch_bounds__(256) void k_route(const int* sel, const float* selv,
        const float* count, float* out, int* cnt, int* toklist, float* wlist) {
    int e = blockIdx.x;
    int tid = threadIdx.x;
    int lane = tid & 63, wid = tid >> 6;
    __shared__ int wsum[4];
    __shared__ float wsumf[4];
    __shared__ int sbase;
    __shared__ float swtot;
    if (tid == 0) { sbase = 0; swtot = 0.f; }
    __syncthreads();
    for (int c = 0; c < TT; c += 256) {
        int t = c + tid;
        int i0 = sel[t * 2], i1 = sel[t * 2 + 1];
        float v0 = selv[t * 2], v1 = selv[t * 2 + 1];
        int f = 0; float vraw = 0.f;
        if (i0 == e) { f = 1; vraw = v0; }
        else if (i1 == e) { f = 1; vraw = v1; }
        float winv = 1.f / (v0 + v1);
        int ps = f;
        float pw = 2.f * vraw;
#pragma unroll
        for (int off = 1; off < 64; off <<= 1) {
            int s_ = __shfl_up(ps, off);
            float w_ = __shfl_up(pw, off);
            if (lane >= off) { ps += s_; pw += w_; }
        }
        if (lane == 63) { wsum[wid] = ps; wsumf[wid] = pw; }
        __syncthreads();
        int wpre = 0; float wpref = 0.f;
        for (int q = 0; q < wid; q++) { wpre += wsum[q]; wpref += wsumf[q]; }
        if (f) {
            int pos = sbase + wpre + ps - 1;
            toklist[e * TT + pos] = t;
            wlist[e * TT + pos] = vraw * winv;
        }
        __syncthreads();
        if (tid == 255) { sbase += wpre + ps; swtot += wpref + pw; }
        __syncthreads();
    }
    if (tid == 0) {
        cnt[e] = sbase;
        out[(size_t)TT * Dm + (size_t)TT * Ec + e] = count[e] + swtot;
    }
}

// ---- gather routed tokens (bf16 src); derives padded offsets from cnt ----
__global__ __launch_bounds__(256) void k_gather(const unsigned short* hs_hi,
        const int* cnt, const int* toklist, const float* wlist,
        unsigned short* xb, int* tcnt, int* tok2slot, float* tok2w) {
    int tid = threadIdx.x;
    int s = blockIdx.x * 2 + (tid >> 7);
    int j = (tid & 127) * 8;
    int e = -1, pos = 0, pad = 0, ce = 0;
#pragma unroll
    for (int q = 0; q < Ec; q++) {
        int cq = cnt[q];
        int span = ((cq + 63) >> 6) * 64;
        if (e < 0 && s < pad + span) { e = q; pos = s - pad; ce = cq; }
        pad += span;
    }
    int tok = -1; float w = 0.f;
    if (e >= 0 && pos < ce) { tok = toklist[e * TT + pos]; w = wlist[e * TT + pos]; }
    if (j == 0 && tok >= 0) {
        int idx = atomicAdd(&tcnt[tok], 1);
        tok2slot[tok * 2 + idx] = s;
        tok2w[tok * 2 + idx] = w;
    }
    short8v o;
    if (tok >= 0) {
        o = *(const short8v*)&hs_hi[(size_t)tok * Dm + j];
    } else {
        o = (short8v)(short)0;
    }
    *(short8v*)&xb[(size_t)s * Dm + j] = o;
}

// ---- FFN MFMA grouped GEMM: 64x128 tiles, BK=64, split-K planes, XCD remap ----
template<int KDIM, int NDIM, int MODE, int KS>
__global__ __launch_bounds__(256) void k_mfma(const unsigned short* Abuf,
        const unsigned short* Wt, const int* cnt, unsigned short* outp) {
    constexpr int NY = NDIM / 128;
    constexpr int KLEN = KDIM / KS;
    constexpr int CPX = (NT64MAX * NY * KS) / 8;
    int bid = blockIdx.x;
    int flat = (bid & 7) * CPX + (bid >> 3);
    int tx = flat / (NY * KS);
    int rem = flat % (NY * KS);
    int y = rem / KS, ks = rem % KS;
    int e = -1, m0 = 0, acc_t = 0, pad = 0;
#pragma unroll
    for (int q = 0; q < Ec; q++) {
        int te = (cnt[q] + 63) >> 6;
        if (e < 0 && tx < acc_t + te) { e = q; m0 = pad + (tx - acc_t) * 64; }
        acc_t += te; pad += te * 64;
    }
    if (e < 0) return;
    int n0 = y * 128;
    int k0 = ks * KLEN;
    __shared__ __align__(16) unsigned short As[64 * 64];    // 8 KB
    __shared__ __align__(16) unsigned short Bs[128 * 64];   // 16 KB
    int tid = threadIdx.x;
    int lane = tid & 63;
    int wid = tid >> 6;
    int wr = wid >> 1, wc = wid & 1;
    int lo = lane & 15, hi = lane >> 4;

    f32x4 acc[2][4];
#pragma unroll
    for (int m = 0; m < 2; m++)
#pragma unroll
        for (int n = 0; n < 4; n++) acc[m][n] = (f32x4)(0.f);

    int arow = tid >> 3;
    int cswz = ((tid & 7) ^ (arow & 7)) * 8;
    const unsigned short* Ag = Abuf + (size_t)(m0 + arow) * KDIM + k0 + cswz;
    const unsigned short* Bg = Wt + (size_t)e * NDIM * KDIM
                               + (size_t)(n0 + arow) * KDIM + k0 + cswz;

    for (int kb = 0; kb < KLEN; kb += 64) {
        gll16(Ag + kb,                          (char*)As + tid * 16);
        gll16(Ag + 32 * (size_t)KDIM + kb,      (char*)As + 4096 + tid * 16);
        gll16(Bg + kb,                          (char*)Bs + tid * 16);
        gll16(Bg + 32 * (size_t)KDIM + kb,      (char*)Bs + 4096 + tid * 16);
        gll16(Bg + 64 * (size_t)KDIM + kb,      (char*)Bs + 8192 + tid * 16);
        gll16(Bg + 96 * (size_t)KDIM + kb,      (char*)Bs + 12288 + tid * 16);
        __syncthreads();
#pragma unroll
        for (int kk = 0; kk < 2; kk++) {
            int csel = ((kk * 4 + hi) ^ (lo & 7)) * 8;
            short8v a[2], b[4];
#pragma unroll
            for (int m = 0; m < 2; m++)
                a[m] = *(const short8v*)&As[(wr * 32 + m * 16 + lo) * 64 + csel];
#pragma unroll
            for (int n = 0; n < 4; n++)
                b[n] = *(const short8v*)&Bs[(wc * 64 + n * 16 + lo) * 64 + csel];
#pragma unroll
            for (int m = 0; m < 2; m++)
#pragma unroll
                for (int n = 0; n < 4; n++)
                    acc[m][n] = __builtin_amdgcn_mfma_f32_16x16x32_bf16(a[m], b[n], acc[m][n], 0, 0, 0);
        }
        __syncthreads();
    }

#pragma unroll
    for (int m = 0; m < 2; m++) {
#pragma unroll
        for (int n = 0; n < 4; n++) {
            int col = n0 + wc * 64 + n * 16 + lo;
#pragma unroll
            for (int r = 0; r < 4; r++) {
                int row = m0 + wr * 32 + m * 16 + hi * 4 + r;
                if (MODE == 0) {
                    outp[(size_t)row * NDIM + col] = bf16_rne(silu_f(acc[m][n][r]));
                } else {
                    outp[((size_t)ks * PADMAX + row) * Dm + col] = bf16_rne(acc[m][n][r]);
                }
            }
        }
    }
}

// ---- combine: out[t] = w0*(P0[s0]+P1[s0]) + w1*(P0[s1]+P1[s1]) ----
__global__ __launch_bounds__(256) void k_combine(const unsigned short* Opart,
        const int* tok2slot, const float* tok2w, float* out) {
    int t = blockIdx.x, tid = threadIdx.x;
    int s0 = tok2slot[t * 2], s1 = tok2slot[t * 2 + 1];
    float w0 = tok2w[t * 2], w1 = tok2w[t * 2 + 1];
    int c = tid * 4;
    ushort4 a0 = *(const ushort4*)&Opart[(size_t)s0 * Dm + c];
    ushort4 a1 = *(const ushort4*)&Opart[((size_t)PADMAX + s0) * Dm + c];
    ushort4 b0 = *(const ushort4*)&Opart[(size_t)s1 * Dm + c];
    ushort4 b1 = *(const ushort4*)&Opart[((size_t)PADMAX + s1) * Dm + c];
    float4 r;
    r.x = w0 * (bf16_to_f(a0.x) + bf16_to_f(a1.x)) + w1 * (bf16_to_f(b0.x) + bf16_to_f(b1.x));
    r.y = w0 * (bf16_to_f(a0.y) + bf16_to_f(a1.y)) + w1 * (bf16_to_f(b0.y) + bf16_to_f(b1.y));
    r.z = w0 * (bf16_to_f(a0.z) + bf16_to_f(a1.z)) + w1 * (bf16_to_f(b0.z) + bf16_to_f(b1.z));
    r.w = w0 * (bf16_to_f(a0.w) + bf16_to_f(a1.w)) + w1 * (bf16_to_f(b0.w) + bf16_to_f(b1.w));
    *(float4*)&out[(size_t)t * Dm + c] = r;
}

extern "C" void kernel_launch(void* const* d_in, const int* in_sizes, int n_in,
                              void* d_out, int out_size, void* d_ws, size_t ws_size,
                              hipStream_t stream) {
    const float* hs    = (const float*)d_in[0];
    const float* X     = (const float*)d_in[1];
    const float* Wmlp  = (const float*)d_in[2];
    const float* Wst   = (const float*)d_in[3];
    const float* convW = (const float*)d_in[4];
    const float* wproj = (const float*)d_in[5];
    const float* W1    = (const float*)d_in[6];
    const float* W2    = (const float*)d_in[7];
    const float* lamb  = (const float*)d_in[8];
    const float* theta = (const float*)d_in[9];
    const float* count = (const float*)d_in[10];
    const float* Ahat  = (const float*)d_in[11];
    float* out = (float*)d_out;
    char* ws = (char*)d_ws;

    // persistent layout
    int*            cnt     = (int*)(ws + 8192);
    float*          S1      = (float*)(ws + 9728);
    int*            toklist = (int*)(ws + 20480);
    float*          wlist   = (float*)(ws + 86016);
    int*            tcnt    = (int*)(ws + 151552);
    int*            tok2slot= (int*)(ws + 159744);
    float*          tok2w   = (float*)(ws + 176128);
    int*            sel     = (int*)(ws + 192512);
    float*          selv    = (float*)(ws + 208896);
    unsigned short* xb      = (unsigned short*)(ws + 237568);   // 10.5 MB
    unsigned short* W1T     = (unsigned short*)(ws + 10723328); // 33.5 MB
    unsigned short* W2T     = (unsigned short*)(ws + 44277760); // 33.5 MB
    unsigned short* hb      = (unsigned short*)(ws + 77832192); // 21 MB, ends 98.8 MB
    unsigned short* Opart   = W1T;                              // dead after up-GEMM

    bool big = ws_size >= (size_t)174063616;   // 166 MiB
    char* G = big ? (ws + 98803712) : (ws + 10723328);
    unsigned short* hs_hi = (unsigned short*)(G);
    unsigned short* hs_lo = (unsigned short*)(G + 4194304);
    unsigned short* WmT_h = (unsigned short*)(G + 8388608);
    unsigned short* WmT_l = (unsigned short*)(G + 8912896);
    unsigned short* WcT_h = (unsigned short*)(G + 9437184);
    unsigned short* WcT_l = (unsigned short*)(G + 9830400);
    unsigned short* xg_h  = (unsigned short*)(G + 10223616);
    unsigned short* xg_l  = (unsigned short*)(G + 11272192);
    float*          ypart = (float*)(G + 12320768);
    unsigned short* n_h   = (unsigned short*)(G + 16515072);
    unsigned short* n_l   = (unsigned short*)(G + 25952256);
    float*          Zb    = (float*)(G + 35389440);
    float*          Gpart = (float*)(G + 54263808);
    float*          xgp   = (float*)(G + 54329344);
    float*          Xpart = (float*)(G + 62717952);

    int prep_blocks = big ? (1489 + 8192) : 1489;
    k_prep<<<prep_blocks, 256, 0, stream>>>(hs, Wmlp, convW, X, Wst, count, lamb,
                                            theta, hs_hi, hs_lo, WmT_h, WmT_l,
                                            WcT_h, WcT_l, Xpart, out, tcnt,
                                            W1, W2, W1T, W2T);
    k_gA<<<DGc / 32, 256, 0, stream>>>(Xpart, convW, Gpart);
    k_s1fin<<<1, 256, 0, stream>>>(Gpart, Ahat, S1);
    gemm4s<64, Dm, 4, 128, 3><<<dim3(TT / 64, 2, 4), 256, 0, stream>>>(
        hs_hi, hs_lo, WmT_h, WmT_l, xgp, nullptr, nullptr);
    k_finsplit<<<TT * DGc / 1024, 256, 0, stream>>>(xgp, xg_h, xg_l);
    gemm4s<64, DGc, 2, 128, 3><<<dim3(TT / 64, 2, 2), 256, 0, stream>>>(
        xg_h, xg_l, WcT_h, WcT_l, ypart, nullptr, nullptr);
    k_l1<<<TT, 256, 0, stream>>>(ypart, S1, Ahat, n_h, n_l);
    gemm4s<64, DGc, 1, 64, 0><<<dim3(TT * Nc / 64, 2, 1), 256, 0, stream>>>(
        n_h, n_l, WcT_h + 65536, WcT_l + 65536, Zb, nullptr, nullptr);
    k_mix2<<<TT, 256, 0, stream>>>(Zb, Ahat, n_h, n_l);
    gemm4s<64, DGc, 1, 64, 0><<<dim3(TT * Nc / 64, 2, 1), 256, 0, stream>>>(
        n_h, n_l, WcT_h + 131072, WcT_l + 131072, Zb, nullptr, nullptr);
    k_mix3<<<TT / 4, 256, 0, stream>>>(Zb, Ahat, wproj, out, sel, selv);
    k_route<<<Ec, 256, 0, stream>>>(sel, selv, count, out, cnt, toklist, wlist);
    k_gather<<<PADMAX / 2, 256, 0, stream>>>(hs_hi, cnt, toklist, wlist,
                                             xb, tcnt, tok2slot, tok2w);
    if (!big) {
        k_tcslab<<<8192, 256, 0, stream>>>(W1, W2, W1T, W2T);
    }
    k_mfma<Dm, Hc, 0, 1><<<NT64MAX * (Hc / 128), 256, 0, stream>>>(
        xb, W1T, cnt, hb);
    k_mfma<Hc, Dm, 1, 2><<<NT64MAX * (Dm / 128) * 2, 256, 0, stream>>>(
        hb, W2T, cnt, Opart);
    k_combine<<<TT, 256, 0, stream>>>(Opart, tok2slot, tok2w, out);
}